// Round 1
// baseline (1286.754 us; speedup 1.0000x reference)
//
#include <hip/hip_runtime.h>
#include <hip/hip_bf16.h>

#define HID 128
#define G4 512      // 4*HID
#define ISZ 75
#define ISZP 76     // padded
#define TT 512
#define BB 512

__device__ __forceinline__ float rcp_fast(float x) { return __builtin_amdgcn_rcpf(x); }
__device__ __forceinline__ float sigmoid_f(float x) { return rcp_fast(1.f + __expf(-x)); }
__device__ __forceinline__ float tanh_f(float x) { return 1.f - 2.f * rcp_fast(__expf(2.f * x) + 1.f); }

// One block per CU (256 blocks, 512 threads). Each block owns 2 batch rows.
// Thread r owns gate row r: W_ih[r,:] and W_hh[r,:] live in VGPRs.
__global__ __launch_bounds__(512, 2) void lstm_persistent(
    const float* __restrict__ x,      // [B, T, ISZ]
    const float* __restrict__ w_ih,   // [512, 75]
    const float* __restrict__ w_hh,   // [512, 128]
    const float* __restrict__ b_ih,   // [512]
    const float* __restrict__ b_hh,   // [512]
    const float* __restrict__ fc_w,   // [10, 128]
    const float* __restrict__ fc_b,   // [10]
    float* __restrict__ out)          // [B, 10]
{
    const int tid = threadIdx.x;
    const int r = tid;                 // gate row 0..511
    const int b0 = blockIdx.x * 2;     // two batch rows per block

    __shared__ __align__(16) float hsh[2][HID];        // current h, per batch
    __shared__ __align__(16) float xsh[2][2][ISZP];    // [buf][batch][i], double-buffered x_t
    __shared__ __align__(16) float gsh[2][G4];         // activated gates, per batch

    // ---- load weights into registers ----
    float wih[ISZP];
#pragma unroll
    for (int k = 0; k < ISZ; ++k) wih[k] = w_ih[r * ISZ + k];
    wih[ISZ] = 0.f;

    float whh[HID];
    {
        const float4* wrow = (const float4*)(w_hh + r * HID);
#pragma unroll
        for (int k = 0; k < HID / 4; ++k) {
            float4 v = wrow[k];
            whh[4 * k + 0] = v.x; whh[4 * k + 1] = v.y;
            whh[4 * k + 2] = v.z; whh[4 * k + 3] = v.w;
        }
    }
    const float bias = b_ih[r] + b_hh[r];

    // ---- init state + first x tile ----
    float c = 0.f;                     // cell state held by threads 0..255 (nb=tid>>7, j=tid&127)
    if (tid < 256) {
        hsh[tid >> 7][tid & 127] = 0.f;
    }
    if (tid < 150) {
        int nb = (tid >= ISZ) ? 1 : 0;
        int k = tid - nb * ISZ;
        xsh[0][nb][k] = x[(size_t)(b0 + nb) * TT * ISZ + k];
    }
    if (tid < 4) xsh[tid >> 1][tid & 1][ISZ] = 0.f;   // zero the pad element
    __syncthreads();

    const float* xb0 = x + (size_t)b0 * TT * ISZ;
    const float* xb1 = x + (size_t)(b0 + 1) * TT * ISZ;

#pragma unroll 1
    for (int t = 0; t < TT; ++t) {
        const int buf = t & 1;

        // ---- phase 1: all 512 threads compute gate r for both batches ----
        float acc0 = bias, acc1 = bias;

        {   // x contribution: 19 float4 broadcast reads per batch
            const float4* x0v = (const float4*)xsh[buf][0];
            const float4* x1v = (const float4*)xsh[buf][1];
#pragma unroll
            for (int k = 0; k < ISZP / 4; ++k) {
                float4 a = x0v[k], b = x1v[k];
                acc0 = fmaf(wih[4 * k + 0], a.x, acc0);
                acc0 = fmaf(wih[4 * k + 1], a.y, acc0);
                acc0 = fmaf(wih[4 * k + 2], a.z, acc0);
                acc0 = fmaf(wih[4 * k + 3], a.w, acc0);
                acc1 = fmaf(wih[4 * k + 0], b.x, acc1);
                acc1 = fmaf(wih[4 * k + 1], b.y, acc1);
                acc1 = fmaf(wih[4 * k + 2], b.z, acc1);
                acc1 = fmaf(wih[4 * k + 3], b.w, acc1);
            }
        }
        {   // h contribution: 32 float4 broadcast reads per batch
            const float4* h0v = (const float4*)hsh[0];
            const float4* h1v = (const float4*)hsh[1];
#pragma unroll
            for (int k = 0; k < HID / 4; ++k) {
                float4 a = h0v[k], b = h1v[k];
                acc0 = fmaf(whh[4 * k + 0], a.x, acc0);
                acc0 = fmaf(whh[4 * k + 1], a.y, acc0);
                acc0 = fmaf(whh[4 * k + 2], a.z, acc0);
                acc0 = fmaf(whh[4 * k + 3], a.w, acc0);
                acc1 = fmaf(whh[4 * k + 0], b.x, acc1);
                acc1 = fmaf(whh[4 * k + 1], b.y, acc1);
                acc1 = fmaf(whh[4 * k + 2], b.z, acc1);
                acc1 = fmaf(whh[4 * k + 3], b.w, acc1);
            }
        }

        // activation: wave-uniform branch (each wave is one gate type; 128 | 64)
        float a0, a1;
        if (r < 256 || r >= 384) {     // i, f, o gates: sigmoid
            a0 = sigmoid_f(acc0);
            a1 = sigmoid_f(acc1);
        } else {                       // g gate: tanh
            a0 = tanh_f(acc0);
            a1 = tanh_f(acc1);
        }
        gsh[0][r] = a0;
        gsh[1][r] = a1;
        __syncthreads();

        // ---- phase 2: threads 0..255 update c,h; threads 256..405 prefetch x ----
        if (tid < 256) {
            const int nb = tid >> 7, j = tid & 127;
            float ig = gsh[nb][j];
            float fg = gsh[nb][HID + j];
            float gg = gsh[nb][2 * HID + j];
            float og = gsh[nb][3 * HID + j];
            c = fmaf(fg, c, ig * gg);
            hsh[nb][j] = og * tanh_f(c);
        } else if (tid < 256 + 150) {
            if (t + 1 < TT) {
                int u = tid - 256;
                int nb = (u >= ISZ) ? 1 : 0;
                int k = u - nb * ISZ;
                const float* xb = nb ? xb1 : xb0;
                xsh[(t + 1) & 1][nb][k] = xb[(size_t)(t + 1) * ISZ + k];
            }
        }
        __syncthreads();
    }

    // ---- epilogue: logits = h @ fc_w^T + fc_b (20 dots of length 128) ----
    if (tid < 20) {
        const int nb = tid / 10, k = tid - 10 * nb;
        float s = fc_b[k];
        const float* w = fc_w + k * HID;
#pragma unroll
        for (int d = 0; d < HID; ++d) s = fmaf(w[d], hsh[nb][d], s);
        out[(b0 + nb) * 10 + k] = s;
    }
}

extern "C" void kernel_launch(void* const* d_in, const int* in_sizes, int n_in,
                              void* d_out, int out_size, void* d_ws, size_t ws_size,
                              hipStream_t stream) {
    const float* x    = (const float*)d_in[0];
    const float* w_ih = (const float*)d_in[1];
    const float* w_hh = (const float*)d_in[2];
    const float* b_ih = (const float*)d_in[3];
    const float* b_hh = (const float*)d_in[4];
    const float* fc_w = (const float*)d_in[5];
    const float* fc_b = (const float*)d_in[6];
    float* out = (float*)d_out;

    lstm_persistent<<<dim3(BB / 2), dim3(512), 0, stream>>>(
        x, w_ih, w_hh, b_ih, b_hh, fc_w, fc_b, out);
}

// Round 3
// 1284.563 us; speedup vs baseline: 1.0017x; 1.0017x over previous
//
#include <hip/hip_runtime.h>
#include <hip/hip_bf16.h>

#define HID 128
#define G4 512      // 4*HID
#define ISZ 75
#define ISZP 76     // padded
#define TT 512
#define BB 512

__device__ __forceinline__ float rcp_fast(float x) { return __builtin_amdgcn_rcpf(x); }
__device__ __forceinline__ float sigmoid_f(float x) { return rcp_fast(1.f + __expf(-x)); }
__device__ __forceinline__ float tanh_f(float x) { return 1.f - 2.f * rcp_fast(__expf(2.f * x) + 1.f); }

// One block per CU (256 blocks, 512 threads). Each block owns 2 batch rows.
// Thread r owns gate row r: W_ih[r,:] and W_hh[r,:] live in VGPRs.
// launch_bounds(512,1): 256 VGPR/thread -> 204 weight floats fit with NO spill.
__global__ __launch_bounds__(512, 1) void lstm_persistent(
    const float* __restrict__ x,      // [B, T, ISZ]
    const float* __restrict__ w_ih,   // [512, 75]
    const float* __restrict__ w_hh,   // [512, 128]
    const float* __restrict__ b_ih,   // [512]
    const float* __restrict__ b_hh,   // [512]
    const float* __restrict__ fc_w,   // [10, 128]
    const float* __restrict__ fc_b,   // [10]
    float* __restrict__ out)          // [B, 10]
{
    const int tid = threadIdx.x;
    const int r = tid;                 // gate row 0..511
    const int b0 = blockIdx.x * 2;     // two batch rows per block

    __shared__ __align__(16) float hsh[2][HID];        // current h, per batch
    __shared__ __align__(16) float xsh[2][2][ISZP];    // [buf][batch][i], double-buffered x_t
    __shared__ __align__(16) float gsh[2][G4];         // activated gates, per batch

    // ---- load weights into registers ----
    float wih[ISZP];
#pragma unroll
    for (int k = 0; k < ISZ; ++k) wih[k] = w_ih[r * ISZ + k];
    wih[ISZ] = 0.f;

    float whh[HID];
    {
        const float4* wrow = (const float4*)(w_hh + r * HID);
#pragma unroll
        for (int k = 0; k < HID / 4; ++k) {
            float4 v = wrow[k];
            whh[4 * k + 0] = v.x; whh[4 * k + 1] = v.y;
            whh[4 * k + 2] = v.z; whh[4 * k + 3] = v.w;
        }
    }
    const float bias = b_ih[r] + b_hh[r];

    // ---- init state + first x tile ----
    float c = 0.f;                     // cell state held by threads 0..255 (nb=tid>>7, j=tid&127)
    if (tid < 256) {
        hsh[tid >> 7][tid & 127] = 0.f;
    }
    if (tid < 150) {
        int nb = (tid >= ISZ) ? 1 : 0;
        int k = tid - nb * ISZ;
        xsh[0][nb][k] = x[(size_t)(b0 + nb) * TT * ISZ + k];
    }
    if (tid < 4) xsh[tid >> 1][tid & 1][ISZ] = 0.f;   // zero the pad element
    __syncthreads();

    const float* xb0 = x + (size_t)b0 * TT * ISZ;
    const float* xb1 = x + (size_t)(b0 + 1) * TT * ISZ;

#pragma unroll 1
    for (int t = 0; t < TT; ++t) {
        const int buf = t & 1;

        // ---- phase 1: all 512 threads compute gate r for both batches ----
        float acc0 = bias, acc1 = bias;

        {   // x contribution: 19 float4 broadcast reads per batch
            const float4* x0v = (const float4*)xsh[buf][0];
            const float4* x1v = (const float4*)xsh[buf][1];
#pragma unroll
            for (int k = 0; k < ISZP / 4; ++k) {
                float4 a = x0v[k], b = x1v[k];
                acc0 = fmaf(wih[4 * k + 0], a.x, acc0);
                acc0 = fmaf(wih[4 * k + 1], a.y, acc0);
                acc0 = fmaf(wih[4 * k + 2], a.z, acc0);
                acc0 = fmaf(wih[4 * k + 3], a.w, acc0);
                acc1 = fmaf(wih[4 * k + 0], b.x, acc1);
                acc1 = fmaf(wih[4 * k + 1], b.y, acc1);
                acc1 = fmaf(wih[4 * k + 2], b.z, acc1);
                acc1 = fmaf(wih[4 * k + 3], b.w, acc1);
            }
        }
        {   // h contribution: 32 float4 broadcast reads per batch
            const float4* h0v = (const float4*)hsh[0];
            const float4* h1v = (const float4*)hsh[1];
#pragma unroll
            for (int k = 0; k < HID / 4; ++k) {
                float4 a = h0v[k], b = h1v[k];
                acc0 = fmaf(whh[4 * k + 0], a.x, acc0);
                acc0 = fmaf(whh[4 * k + 1], a.y, acc0);
                acc0 = fmaf(whh[4 * k + 2], a.z, acc0);
                acc0 = fmaf(whh[4 * k + 3], a.w, acc0);
                acc1 = fmaf(whh[4 * k + 0], b.x, acc1);
                acc1 = fmaf(whh[4 * k + 1], b.y, acc1);
                acc1 = fmaf(whh[4 * k + 2], b.z, acc1);
                acc1 = fmaf(whh[4 * k + 3], b.w, acc1);
            }
        }

        // activation: wave-uniform branch (each wave is one gate type; 128 | 64)
        float a0, a1;
        if (r < 256 || r >= 384) {     // i, f, o gates: sigmoid
            a0 = sigmoid_f(acc0);
            a1 = sigmoid_f(acc1);
        } else {                       // g gate: tanh
            a0 = tanh_f(acc0);
            a1 = tanh_f(acc1);
        }
        gsh[0][r] = a0;
        gsh[1][r] = a1;
        __syncthreads();

        // ---- phase 2: threads 0..255 update c,h; threads 256..405 prefetch x ----
        if (tid < 256) {
            const int nb = tid >> 7, j = tid & 127;
            float ig = gsh[nb][j];
            float fg = gsh[nb][HID + j];
            float gg = gsh[nb][2 * HID + j];
            float og = gsh[nb][3 * HID + j];
            c = fmaf(fg, c, ig * gg);
            hsh[nb][j] = og * tanh_f(c);
        } else if (tid < 256 + 150) {
            if (t + 1 < TT) {
                int u = tid - 256;
                int nb = (u >= ISZ) ? 1 : 0;
                int k = u - nb * ISZ;
                const float* xb = nb ? xb1 : xb0;
                xsh[(t + 1) & 1][nb][k] = xb[(size_t)(t + 1) * ISZ + k];
            }
        }
        __syncthreads();
    }

    // ---- epilogue: logits = h @ fc_w^T + fc_b (20 dots of length 128) ----
    if (tid < 20) {
        const int nb = tid / 10, k = tid - 10 * nb;
        float s = fc_b[k];
        const float* w = fc_w + k * HID;
#pragma unroll
        for (int d = 0; d < HID; ++d) s = fmaf(w[d], hsh[nb][d], s);
        out[(b0 + nb) * 10 + k] = s;
    }
}

extern "C" void kernel_launch(void* const* d_in, const int* in_sizes, int n_in,
                              void* d_out, int out_size, void* d_ws, size_t ws_size,
                              hipStream_t stream) {
    const float* x    = (const float*)d_in[0];
    const float* w_ih = (const float*)d_in[1];
    const float* w_hh = (const float*)d_in[2];
    const float* b_ih = (const float*)d_in[3];
    const float* b_hh = (const float*)d_in[4];
    const float* fc_w = (const float*)d_in[5];
    const float* fc_b = (const float*)d_in[6];
    float* out = (float*)d_out;

    lstm_persistent<<<dim3(BB / 2), dim3(512), 0, stream>>>(
        x, w_ih, w_hh, b_ih, b_hh, fc_w, fc_b, out);
}

// Round 4
// 601.013 us; speedup vs baseline: 2.1410x; 2.1373x over previous
//
#include <hip/hip_runtime.h>
#include <hip/hip_bf16.h>

#define HID 128
#define ISZ 75
#define KDIM 224      // padded K: 128 (h) + 75 (x) + 21 zero pad
#define KC 7          // k-chunks of 32
#define TT 512
#define BB 512
#define ZSTR 232      // z row stride in f16 (224 + 8 pad -> 2-way banks only)

typedef _Float16 half8 __attribute__((ext_vector_type(8)));
typedef float floatx4 __attribute__((ext_vector_type(4)));

__device__ __forceinline__ float rcp_fast(float x) { return __builtin_amdgcn_rcpf(x); }
__device__ __forceinline__ float sigmoid_f(float x) { return rcp_fast(1.f + __expf(-x)); }
__device__ __forceinline__ float tanh_f(float x) { return 1.f - 2.f * rcp_fast(__expf(2.f * x) + 1.f); }

// 256 blocks (1/CU) x 1024 threads (16 waves). Block owns 2 batch rows.
// Per step: P^T[512 gates x 16 batch(2 real)] = W'[512 x 224] @ z^T[224 x 16]
// via mfma_f32_16x16x32_f16. W' fragments persistent in VGPRs
// (wave w owns gate rows [32w, 32w+32): 2 m-tiles x 7 k-chunks).
// Fragment layout (m89-verified convention):
//   A[m][k]: lane holds m = lane&15,        k = (lane>>4)*8 + e
//   B[k][n]: lane holds n = lane&15 (batch), k = (lane>>4)*8 + e
//   D[m][n]: lane holds n = lane&15 (batch), m = (lane>>4)*4 + j
__global__ __launch_bounds__(1024, 1) void lstm_mfma(
    const float* __restrict__ x,      // [B, T, 75]
    const float* __restrict__ w_ih,   // [512, 75]
    const float* __restrict__ w_hh,   // [512, 128]
    const float* __restrict__ b_ih,   // [512]
    const float* __restrict__ b_hh,   // [512]
    const float* __restrict__ fc_w,   // [10, 128]
    const float* __restrict__ fc_b,   // [10]
    float* __restrict__ out)          // [B, 10]
{
    const int tid  = threadIdx.x;
    const int wave = tid >> 6;
    const int lane = tid & 63;
    const int l15  = lane & 15;
    const int l4   = lane >> 4;
    const int b0   = blockIdx.x * 2;
    const int wb   = wave * 32;       // this wave's gate-row base

    __shared__ __align__(16) _Float16 zsh[16][ZSTR];   // z = [h | x_t] per batch row (rows 2-15 unused garbage cols)
    __shared__ __align__(16) float    psh[2][512];     // pre-activation gates per batch

    // ---- zero zsh (h zone must start 0; pad zones must be 0 for real rows) ----
    {
        int* zi = (int*)&zsh[0][0];
        const int n4 = 16 * ZSTR / 2;                  // f16 pairs
        for (int i = tid; i < n4; i += 1024) zi[i] = 0;
    }
    __syncthreads();

    // ---- stage x_0 into z x-zone ----
    if (tid >= 256 && tid < 256 + 2 * ISZ) {
        int u = tid - 256;
        int nb = (u >= ISZ) ? 1 : 0;
        int k = u - nb * ISZ;
        zsh[nb][HID + k] = (_Float16)x[((size_t)(b0 + nb) * TT) * ISZ + k];
    }

    // ---- build persistent W' fragments + bias accum-init ----
    half8  wfr[2][KC];
    floatx4 bias[2];
#pragma unroll
    for (int mt = 0; mt < 2; ++mt) {
        const int R = wb + mt * 16 + l15;              // gate row this lane holds for A
#pragma unroll
        for (int kc = 0; kc < KC; ++kc) {
            half8 f;
            const int kbase = kc * 32 + l4 * 8;
#pragma unroll
            for (int e = 0; e < 8; ++e) {
                const int k = kbase + e;
                float v = 0.f;
                if (k < HID)            v = w_hh[R * HID + k];
                else if (k < HID + ISZ) v = w_ih[R * ISZ + (k - HID)];
                f[e] = (_Float16)v;
            }
            wfr[mt][kc] = f;
        }
        floatx4 bf;
#pragma unroll
        for (int j = 0; j < 4; ++j) {
            const int g = wb + mt * 16 + l4 * 4 + j;   // gate row this lane holds for D
            bf[j] = b_ih[g] + b_hh[g];
        }
        bias[mt] = bf;
    }

    float c = 0.f;    // cell state: threads 0..255 own (nb = tid>>7, j = tid&127)
    __syncthreads();

#pragma unroll 1
    for (int t = 0; t < TT; ++t) {
        // issue next-step x load early (latency hides under MFMA phase)
        float xpre = 0.f;
        int xnb = 0, xk = 0;
        const bool xthr = (tid >= 256 && tid < 256 + 2 * ISZ);
        if (xthr) {
            int u = tid - 256;
            xnb = (u >= ISZ) ? 1 : 0;
            xk = u - xnb * ISZ;
            int tn = (t + 1 < TT) ? (t + 1) : t;
            xpre = x[((size_t)(b0 + xnb) * TT + tn) * ISZ + xk];
        }

        // ---- phase A: 14 MFMAs against z in LDS ----
        floatx4 acc0 = bias[0], acc1 = bias[1];
#pragma unroll
        for (int kc = 0; kc < KC; ++kc) {
            half8 z = *(const half8*)&zsh[l15][kc * 32 + l4 * 8];
            acc0 = __builtin_amdgcn_mfma_f32_16x16x32_f16(wfr[0][kc], z, acc0, 0, 0, 0);
            acc1 = __builtin_amdgcn_mfma_f32_16x16x32_f16(wfr[1][kc], z, acc1, 0, 0, 0);
        }
        if (l15 < 2) {   // only batch cols 0,1 are real
            *(floatx4*)&psh[l15][wb + l4 * 4]      = acc0;
            *(floatx4*)&psh[l15][wb + 16 + l4 * 4] = acc1;
        }
        __syncthreads();

        // ---- phase B: gate activation + c/h update (threads 0-255), x stage (256-405) ----
        if (tid < 256) {
            const int nb = tid >> 7, j = tid & 127;
            float pi = psh[nb][j];
            float pf = psh[nb][HID + j];
            float pg = psh[nb][2 * HID + j];
            float po = psh[nb][3 * HID + j];
            float ig = sigmoid_f(pi);
            float fg = sigmoid_f(pf);
            float gg = tanh_f(pg);
            float og = sigmoid_f(po);
            c = fmaf(fg, c, ig * gg);
            zsh[nb][j] = (_Float16)(og * tanh_f(c));   // h_t as f16 for next step
        } else if (xthr && (t + 1 < TT)) {
            zsh[xnb][HID + xk] = (_Float16)xpre;
        }
        __syncthreads();
    }

    // ---- epilogue: logits = h @ fc_w^T + fc_b ----
    if (tid < 20) {
        const int nb = tid / 10, k = tid - nb * 10;
        float s = fc_b[k];
        const float* w = fc_w + k * HID;
#pragma unroll
        for (int d = 0; d < HID; ++d) s = fmaf(w[d], (float)zsh[nb][d], s);
        out[(b0 + nb) * 10 + k] = s;
    }
}

extern "C" void kernel_launch(void* const* d_in, const int* in_sizes, int n_in,
                              void* d_out, int out_size, void* d_ws, size_t ws_size,
                              hipStream_t stream) {
    const float* x    = (const float*)d_in[0];
    const float* w_ih = (const float*)d_in[1];
    const float* w_hh = (const float*)d_in[2];
    const float* b_ih = (const float*)d_in[3];
    const float* b_hh = (const float*)d_in[4];
    const float* fc_w = (const float*)d_in[5];
    const float* fc_b = (const float*)d_in[6];
    float* out = (float*)d_out;

    lstm_mfma<<<dim3(BB / 2), dim3(1024), 0, stream>>>(
        x, w_ih, w_hh, b_ih, b_hh, fc_w, fc_b, out);
}